// Round 3
// baseline (4533.492 us; speedup 1.0000x reference)
//
#include <hip/hip_runtime.h>
#include <math.h>

#define BB 1024
#define TT 512
#define FF 32
#define HH 64
#define GG 256   // 4H
#define TC 32
#define NCHUNK (TT/TC)   // 16
#define EPSBN 1e-3f

// ---------------- fold1: per-layer BN vectors + attention vector ----------------
__global__ void fold1_kernel(const float* __restrict__ gamma, const float* __restrict__ beta,
                             const float* __restrict__ mean, const float* __restrict__ var,
                             const float* __restrict__ attw, const float* __restrict__ attv,
                             float* __restrict__ s_out, float* __restrict__ ab_out,
                             float* __restrict__ wv_out) {
    int d = threadIdx.x; // 64 threads
    float s = gamma[d] * rsqrtf(var[d] + EPSBN);
    float ab = beta[d] - mean[d] * s;
    float wvr = 0.f;
    for (int e = 0; e < HH; ++e) wvr += attw[d * HH + e] * attv[e];
    s_out[d] = s;
    ab_out[d] = ab;
    wv_out[d] = s * wvr;
}

// ---------------- fold2: fold previous layer's BN into next W, b ----------------
__global__ void fold2_kernel(const float* __restrict__ W, const float* __restrict__ b,
                             const float* __restrict__ s_prev, const float* __restrict__ ab_prev,
                             float* __restrict__ Wp, float* __restrict__ bp) {
    int g = threadIdx.x; // 256 threads
    float bacc = b[g];
    for (int d = 0; d < HH; ++d) {
        float w = W[d * GG + g];
        bacc += ab_prev[d] * w;
        Wp[d * GG + g] = s_prev[d] * w;
    }
    bp[g] = bacc;
}

// ---------------- init per-call state ----------------
__global__ void init_kernel(float* st_h, float* st_c, float* st_acc, float* st_m, float* st_d) {
    int i = blockIdx.x * blockDim.x + threadIdx.x;
    int n = 3 * BB * HH;
    if (i < n) { st_h[i] = 0.f; st_c[i] = 0.f; st_acc[i] = 0.f; }
    if (i < 3 * BB) { st_m[i] = -3.0e38f; st_d[i] = 0.f; }
}

// ---------------- xz GEMM (multi-segment) ----------------
struct XzArgs {
    const float* in[3];
    long sB[3], sT[3];
    const float* W[3];
    const float* bias[3];
    float* out[3];
    int K[3];
    int nseg;
};

template<int K>
__device__ __forceinline__ void xz_body(const float* __restrict__ inb, long sT,
                                        const float* __restrict__ Wt, const float* __restrict__ bias,
                                        float* __restrict__ outb, float* in_s, int tid) {
    constexpr int K4 = K / 4;
    constexpr int NF4 = TC * K4;
    for (int f4 = tid; f4 < NF4; f4 += 256) {
        int r = f4 / K4, kk = (f4 % K4) * 4;
        *reinterpret_cast<float4*>(&in_s[r * K + kk]) =
            *reinterpret_cast<const float4*>(inb + (long)r * sT + kk);
    }
    float wreg[K];
#pragma unroll
    for (int k = 0; k < K; ++k) wreg[k] = Wt[k * GG + tid];
    float bg = bias[tid];
    __syncthreads();
    for (int r = 0; r < TC; r += 2) {   // 2-row tile: 2 independent acc chains
        float a0 = bg, a1 = bg;
#pragma unroll
        for (int k4 = 0; k4 < K4; ++k4) {
            float4 p = *reinterpret_cast<const float4*>(&in_s[r * K + k4 * 4]);
            float4 q = *reinterpret_cast<const float4*>(&in_s[(r + 1) * K + k4 * 4]);
            a0 = fmaf(p.x, wreg[k4*4+0], a0); a1 = fmaf(q.x, wreg[k4*4+0], a1);
            a0 = fmaf(p.y, wreg[k4*4+1], a0); a1 = fmaf(q.y, wreg[k4*4+1], a1);
            a0 = fmaf(p.z, wreg[k4*4+2], a0); a1 = fmaf(q.z, wreg[k4*4+2], a1);
            a0 = fmaf(p.w, wreg[k4*4+3], a0); a1 = fmaf(q.w, wreg[k4*4+3], a1);
        }
        outb[r * GG + tid] = a0;
        outb[(r + 1) * GG + tid] = a1;
    }
}

__global__ __launch_bounds__(256, 4) void xz_multi(XzArgs A) {
    __shared__ float in_s[TC * 64];
    int seg = blockIdx.x >> 10;
    int bid = blockIdx.x & 1023;
    int tid = threadIdx.x;
    const float* inb = A.in[seg] + (long)bid * A.sB[seg];
    float* outb = A.out[seg] + (size_t)bid * (TC * GG);
    if (A.K[seg] == 32)
        xz_body<32>(inb, A.sT[seg], A.W[seg], A.bias[seg], outb, in_s, tid);
    else
        xz_body<64>(inb, A.sT[seg], A.W[seg], A.bias[seg], outb, in_s, tid);
}

// ---------------- DPP full-wave (64) sum; returns total broadcast via readlane ----------------
__device__ __forceinline__ float wsum64(float v) {
    v += __int_as_float(__builtin_amdgcn_update_dpp(0, __float_as_int(v), 0x111, 0xf, 0xf, true));  // row_shr:1
    v += __int_as_float(__builtin_amdgcn_update_dpp(0, __float_as_int(v), 0x112, 0xf, 0xf, true));  // row_shr:2
    v += __int_as_float(__builtin_amdgcn_update_dpp(0, __float_as_int(v), 0x114, 0xf, 0xf, true));  // row_shr:4
    v += __int_as_float(__builtin_amdgcn_update_dpp(0, __float_as_int(v), 0x118, 0xf, 0xf, true));  // row_shr:8
    v += __int_as_float(__builtin_amdgcn_update_dpp(0, __float_as_int(v), 0x142, 0xa, 0xf, false)); // row_bcast:15
    v += __int_as_float(__builtin_amdgcn_update_dpp(0, __float_as_int(v), 0x143, 0xc, 0xf, false)); // row_bcast:31
    return __int_as_float(__builtin_amdgcn_readlane(__float_as_int(v), 63));
}

// ---------------- recurrent kernel: block = 4 waves = 1 batch row of 1 layer-chunk ----------------
// wave w = gate w (i,f,g,o); lane j = hidden unit j. U slice 64 regs/lane.
// h broadcast via uniform LDS float4 reads; gates exchanged via LDS; DPP softmax in wave0.
struct RecArgs {
    const float* xz[3];
    const float* U[3];
    float* Hout[3];           // nullptr -> skip
    float* st_h[3]; float* st_c[3]; float* st_acc[3];
    float* st_m[3]; float* st_d[3];
    const float* wv[3]; const float* abv[3]; const float* sbn[3];
    float* a_out[3];
    int last[3];
    int nseg;
};

__global__ __launch_bounds__(256, 4) void rec_multi(RecArgs A) {
    __shared__ float hs[2][64];
    __shared__ float zs[4][64];

    int seg = blockIdx.x >> 10;
    int b   = blockIdx.x & 1023;
    int tid = threadIdx.x;
    int w = tid >> 6;    // gate
    int j = tid & 63;    // unit

    const float* U = A.U[seg];
    float u[64];
    const float* Ucol = U + (w << 6) + j;
#pragma unroll
    for (int k = 0; k < 64; ++k) u[k] = Ucol[k * GG];

    int gi = (b << 6) + j;
    float c = A.st_c[seg][gi];
    float hlast = A.st_h[seg][gi];
    float accv = 0.f, m_b = 0.f, d_b = 0.f, wvj = 0.f;
    if (w == 0) {
        accv = A.st_acc[seg][gi];
        m_b  = A.st_m[seg][b];
        d_b  = A.st_d[seg][b];
        wvj  = A.wv[seg][j];
        hs[0][j] = hlast;
    }
    __syncthreads();

    const float* xzb = A.xz[seg] + (size_t)b * TC * GG + tid;
    float* Hob = A.Hout[seg] ? (A.Hout[seg] + (size_t)b * TC * HH + j) : (float*)0;

    float xv = xzb[0];
    for (int t = 0; t < TC; ++t) {
        float xnext = (t + 1 < TC) ? xzb[(t + 1) * GG] : 0.f;

        float acc = xv;
        const float* hp = hs[t & 1];
#pragma unroll
        for (int k4 = 0; k4 < 16; ++k4) {
            float4 h4 = *reinterpret_cast<const float4*>(&hp[k4 * 4]);   // uniform -> broadcast
            acc = fmaf(h4.x, u[k4*4+0], acc);
            acc = fmaf(h4.y, u[k4*4+1], acc);
            acc = fmaf(h4.z, u[k4*4+2], acc);
            acc = fmaf(h4.w, u[k4*4+3], acc);
        }
        float z = (w == 2) ? fmaxf(acc, 0.f)
                           : __fdividef(1.f, 1.f + __expf(-acc));
        zs[w][j] = z;
        __syncthreads();

        float zi = zs[0][j], zf = zs[1][j], zg = zs[2][j], zo = zs[3][j];
        c = fmaf(zf, c, zi * zg);
        float h = zo * fmaxf(c, 0.f);
        hlast = h;

        if (w == 2) hs[(t & 1) ^ 1][j] = h;        // wave2 publishes h for next step
        if (w == 1 && Hob) Hob[t * HH] = h;        // wave1 writes Hout
        if (w == 0) {                              // wave0: online-softmax attention
            float sc = wsum64(h * wvj);
            float mnew = fmaxf(m_b, sc);
            float corr = __expf(m_b - mnew);
            float p = __expf(sc - mnew);
            d_b = fmaf(d_b, corr, p);
            accv = fmaf(accv, corr, p * h);
            m_b = mnew;
        }
        __syncthreads();
        xv = xnext;
    }

    if (w == 2) { A.st_c[seg][gi] = c; A.st_h[seg][gi] = hlast; }
    if (w == 0) {
        A.st_acc[seg][gi] = accv;
        if (j == 0) { A.st_m[seg][b] = m_b; A.st_d[seg][b] = d_b; }
        if (A.last[seg]) {
            A.a_out[seg][gi] = A.sbn[seg][j] * __fdividef(accv, d_b) + A.abv[seg][j];
        }
    }
}

// ---------------- final: out[b] = db + sum_{l,j} a[l][b][j]*dw[l*64+j] ----------------
__global__ void final_kernel(const float* __restrict__ a, const float* __restrict__ dw,
                             const float* __restrict__ db, float* __restrict__ out) {
    int b = blockIdx.x * blockDim.x + threadIdx.x;
    if (b >= BB) return;
    float acc = db[0];
    for (int l = 0; l < 3; ++l)
        for (int j = 0; j < HH; ++j)
            acc += a[(l * BB + b) * HH + j] * dw[l * HH + j];
    out[b] = acc;
}

extern "C" void kernel_launch(void* const* d_in, const int* in_sizes, int n_in,
                              void* d_out, int out_size, void* d_ws, size_t ws_size,
                              hipStream_t stream) {
    (void)in_sizes; (void)n_in; (void)out_size; (void)ws_size;
    const float* x = (const float*)d_in[0];
    const float* w[3]    = {(const float*)d_in[1],  (const float*)d_in[10], (const float*)d_in[19]};
    const float* uu[3]   = {(const float*)d_in[2],  (const float*)d_in[11], (const float*)d_in[20]};
    const float* bi[3]   = {(const float*)d_in[3],  (const float*)d_in[12], (const float*)d_in[21]};
    const float* gam[3]  = {(const float*)d_in[4],  (const float*)d_in[13], (const float*)d_in[22]};
    const float* bet[3]  = {(const float*)d_in[5],  (const float*)d_in[14], (const float*)d_in[23]};
    const float* mea[3]  = {(const float*)d_in[6],  (const float*)d_in[15], (const float*)d_in[24]};
    const float* var[3]  = {(const float*)d_in[7],  (const float*)d_in[16], (const float*)d_in[25]};
    const float* atw[3]  = {(const float*)d_in[8],  (const float*)d_in[17], (const float*)d_in[26]};
    const float* atv[3]  = {(const float*)d_in[9],  (const float*)d_in[18], (const float*)d_in[27]};
    const float* dw = (const float*)d_in[28];
    const float* db = (const float*)d_in[29];

    float* ws = (float*)d_ws;
    size_t off = 0;
    float* XZb[3]; for (int l = 0; l < 3; ++l) { XZb[l] = ws + off; off += (size_t)BB * TC * GG; }
    float* Hb[2];  for (int l = 0; l < 2; ++l) { Hb[l]  = ws + off; off += (size_t)BB * TC * HH; }
    float* st_h  = ws + off; off += 3 * BB * HH;
    float* st_c  = ws + off; off += 3 * BB * HH;
    float* st_ac = ws + off; off += 3 * BB * HH;
    float* st_m  = ws + off; off += 3 * BB;
    float* st_d  = ws + off; off += 3 * BB;
    float* s_ws  = ws + off; off += 3 * HH;
    float* ab_ws = ws + off; off += 3 * HH;
    float* wv_ws = ws + off; off += 3 * HH;
    float* W2p   = ws + off; off += HH * GG;
    float* W3p   = ws + off; off += HH * GG;
    float* b2p   = ws + off; off += GG;
    float* b3p   = ws + off; off += GG;
    float* a_ws  = ws + off; off += 3 * BB * HH;

    for (int l = 0; l < 3; ++l)
        fold1_kernel<<<1, 64, 0, stream>>>(gam[l], bet[l], mea[l], var[l], atw[l], atv[l],
                                           s_ws + l * HH, ab_ws + l * HH, wv_ws + l * HH);
    fold2_kernel<<<1, 256, 0, stream>>>(w[1], bi[1], s_ws + 0 * HH, ab_ws + 0 * HH, W2p, b2p);
    fold2_kernel<<<1, 256, 0, stream>>>(w[2], bi[2], s_ws + 1 * HH, ab_ws + 1 * HH, W3p, b3p);
    init_kernel<<<(3 * BB * HH + 255) / 256, 256, 0, stream>>>(st_h, st_c, st_ac, st_m, st_d);

    const float* Wl[3]  = {w[0], W2p, W3p};
    const float* bl[3]  = {bi[0], b2p, b3p};

    // software pipeline: at step s, layer l processes chunk s-l
    for (int s = 0; s <= NCHUNK - 1 + 2; ++s) {
        XzArgs xa; RecArgs ra;
        int nseg = 0;
        for (int l = 0; l < 3; ++l) {
            int cpos = s - l;
            if (cpos < 0 || cpos >= NCHUNK) continue;
            // xz segment
            if (l == 0) {
                xa.in[nseg] = x + (size_t)cpos * TC * FF;
                xa.sB[nseg] = (long)TT * FF; xa.sT[nseg] = FF; xa.K[nseg] = 32;
            } else {
                xa.in[nseg] = Hb[l - 1];
                xa.sB[nseg] = (long)TC * HH; xa.sT[nseg] = HH; xa.K[nseg] = 64;
            }
            xa.W[nseg] = Wl[l]; xa.bias[nseg] = bl[l]; xa.out[nseg] = XZb[l];
            // rec segment
            ra.xz[nseg] = XZb[l];
            ra.U[nseg]  = uu[l];
            ra.Hout[nseg] = (l < 2) ? Hb[l] : (float*)0;
            ra.st_h[nseg] = st_h + l * BB * HH;
            ra.st_c[nseg] = st_c + l * BB * HH;
            ra.st_acc[nseg] = st_ac + l * BB * HH;
            ra.st_m[nseg] = st_m + l * BB;
            ra.st_d[nseg] = st_d + l * BB;
            ra.wv[nseg] = wv_ws + l * HH;
            ra.abv[nseg] = ab_ws + l * HH;
            ra.sbn[nseg] = s_ws + l * HH;
            ra.a_out[nseg] = a_ws + l * BB * HH;
            ra.last[nseg] = (cpos == NCHUNK - 1) ? 1 : 0;
            ++nseg;
        }
        if (!nseg) continue;
        xa.nseg = nseg; ra.nseg = nseg;
        xz_multi<<<nseg * BB, 256, 0, stream>>>(xa);
        rec_multi<<<nseg * BB, 256, 0, stream>>>(ra);
    }
    final_kernel<<<(BB + 255) / 256, 256, 0, stream>>>(a_ws, dw, db, (float*)d_out);
}

// Round 4
// 2660.578 us; speedup vs baseline: 1.7040x; 1.7040x over previous
//
#include <hip/hip_runtime.h>
#include <math.h>

#define BB 1024
#define TT 512
#define FF 32
#define HH 64
#define GG 256   // 4H
#define TC 64
#define NCHUNK (TT/TC)   // 8
#define EPSBN 1e-3f

// ---------------- fold1: per-layer BN vectors + attention vector ----------------
__global__ void fold1_kernel(const float* __restrict__ gamma, const float* __restrict__ beta,
                             const float* __restrict__ mean, const float* __restrict__ var,
                             const float* __restrict__ attw, const float* __restrict__ attv,
                             float* __restrict__ s_out, float* __restrict__ ab_out,
                             float* __restrict__ wv_out) {
    int d = threadIdx.x; // 64 threads
    float s = gamma[d] * rsqrtf(var[d] + EPSBN);
    float ab = beta[d] - mean[d] * s;
    float wvr = 0.f;
    for (int e = 0; e < HH; ++e) wvr += attw[d * HH + e] * attv[e];
    s_out[d] = s;
    ab_out[d] = ab;
    wv_out[d] = s * wvr;
}

// ---------------- fold2: fold previous layer's BN into next W, b ----------------
__global__ void fold2_kernel(const float* __restrict__ W, const float* __restrict__ b,
                             const float* __restrict__ s_prev, const float* __restrict__ ab_prev,
                             float* __restrict__ Wp, float* __restrict__ bp) {
    int g = threadIdx.x; // 256 threads
    float bacc = b[g];
    for (int d = 0; d < HH; ++d) {
        float w = W[d * GG + g];
        bacc += ab_prev[d] * w;
        Wp[d * GG + g] = s_prev[d] * w;
    }
    bp[g] = bacc;
}

// ---------------- init per-call state ----------------
__global__ void init_kernel(float* st_h, float* st_c, float* st_acc, float* st_m, float* st_d) {
    int i = blockIdx.x * blockDim.x + threadIdx.x;
    int n = 3 * BB * HH;
    if (i < n) { st_h[i] = 0.f; st_c[i] = 0.f; st_acc[i] = 0.f; }
    if (i < 3 * BB) { st_m[i] = -3.0e38f; st_d[i] = 0.f; }
}

// ---------------- DPP full-wave (64) sum; total broadcast via readlane ----------------
__device__ __forceinline__ float wsum64(float v) {
    v += __int_as_float(__builtin_amdgcn_update_dpp(0, __float_as_int(v), 0x111, 0xf, 0xf, true));  // row_shr:1
    v += __int_as_float(__builtin_amdgcn_update_dpp(0, __float_as_int(v), 0x112, 0xf, 0xf, true));  // row_shr:2
    v += __int_as_float(__builtin_amdgcn_update_dpp(0, __float_as_int(v), 0x114, 0xf, 0xf, true));  // row_shr:4
    v += __int_as_float(__builtin_amdgcn_update_dpp(0, __float_as_int(v), 0x118, 0xf, 0xf, true));  // row_shr:8
    v += __int_as_float(__builtin_amdgcn_update_dpp(0, __float_as_int(v), 0x142, 0xa, 0xf, false)); // row_bcast:15
    v += __int_as_float(__builtin_amdgcn_update_dpp(0, __float_as_int(v), 0x143, 0xc, 0xf, false)); // row_bcast:31
    return __int_as_float(__builtin_amdgcn_readlane(__float_as_int(v), 63));
}

// ---------------- fused recurrent kernel: x@W + h@U per timestep, no XZ buffer ----------
// Block = 4 waves = 1 batch row of 1 layer-chunk. Wave w = gate w; lane j = unit j.
// Lane holds W column (wx[K]) and U column (u[64]); x_t and h broadcast from LDS.
struct RecFArgs {
    const float* xin[3]; long sB[3]; int K[3];
    const float* W[3]; const float* U[3]; const float* bias[3];
    float* Hout[3];              // nullptr -> skip
    float* st_h[3]; float* st_c[3]; float* st_acc[3];
    float* st_m[3]; float* st_d[3];
    const float* wv[3]; const float* abv[3]; const float* sbn[3];
    float* a_out[3];
    int last[3];
};

template<int K>
__device__ void rec_seg(const RecFArgs& A, int seg, int b, int tid,
                        float* xs, float (*hs)[64], float (*zs)[64]) {
    int w = tid >> 6, j = tid & 63;
    int col = (w << 6) + j;

    const float* Wp = A.W[seg];
    const float* Up = A.U[seg];
    float wx[K], u[64];
#pragma unroll
    for (int k = 0; k < K; ++k) wx[k] = Wp[k * GG + col];
#pragma unroll
    for (int k = 0; k < 64; ++k) u[k] = Up[k * GG + col];
    float bg = A.bias[seg][col];

    // stage input chunk (contiguous TC*K floats per batch row)
    const float4* xb4 = reinterpret_cast<const float4*>(A.xin[seg] + (long)b * A.sB[seg]);
    constexpr int NF4 = TC * K / 4;
    for (int i = tid; i < NF4; i += 256)
        reinterpret_cast<float4*>(xs)[i] = xb4[i];

    int gi = (b << 6) + j;
    float c = A.st_c[seg][gi];
    float hlast = A.st_h[seg][gi];
    float accv = 0.f, m_b = 0.f, d_b = 0.f, wvj = 0.f;
    if (w == 0) {
        accv = A.st_acc[seg][gi];
        m_b  = A.st_m[seg][b];
        d_b  = A.st_d[seg][b];
        wvj  = A.wv[seg][j];
        hs[0][j] = hlast;
    }
    __syncthreads();

    float* Hob = A.Hout[seg] ? A.Hout[seg] + (size_t)b * TC * HH + j : (float*)0;

    for (int t = 0; t < TC; ++t) {
        float acc = bg;
        const float* xr = xs + t * K;
#pragma unroll
        for (int k4 = 0; k4 < K / 4; ++k4) {
            float4 x4 = *reinterpret_cast<const float4*>(xr + k4 * 4);  // uniform -> broadcast
            acc = fmaf(x4.x, wx[k4*4+0], acc);
            acc = fmaf(x4.y, wx[k4*4+1], acc);
            acc = fmaf(x4.z, wx[k4*4+2], acc);
            acc = fmaf(x4.w, wx[k4*4+3], acc);
        }
        const float* hp = hs[t & 1];
#pragma unroll
        for (int k4 = 0; k4 < 16; ++k4) {
            float4 h4 = *reinterpret_cast<const float4*>(hp + k4 * 4);  // uniform -> broadcast
            acc = fmaf(h4.x, u[k4*4+0], acc);
            acc = fmaf(h4.y, u[k4*4+1], acc);
            acc = fmaf(h4.z, u[k4*4+2], acc);
            acc = fmaf(h4.w, u[k4*4+3], acc);
        }
        float z = (w == 2) ? fmaxf(acc, 0.f)
                           : __fdividef(1.f, 1.f + __expf(-acc));
        zs[w][j] = z;
        __syncthreads();

        float zi = zs[0][j], zf = zs[1][j], zg = zs[2][j], zo = zs[3][j];
        c = fmaf(zf, c, zi * zg);
        float h = zo * fmaxf(c, 0.f);
        hlast = h;

        if (w == 2) hs[(t & 1) ^ 1][j] = h;      // publish h for next step
        if (w == 1 && Hob) Hob[t * HH] = h;      // h for next layer
        if (w == 0) {                            // online-softmax attention
            float sc = wsum64(h * wvj);
            float mnew = fmaxf(m_b, sc);
            float corr = __expf(m_b - mnew);
            float p = __expf(sc - mnew);
            d_b = fmaf(d_b, corr, p);
            accv = fmaf(accv, corr, p * h);
            m_b = mnew;
        }
        __syncthreads();
    }

    if (w == 2) { A.st_c[seg][gi] = c; A.st_h[seg][gi] = hlast; }
    if (w == 0) {
        A.st_acc[seg][gi] = accv;
        if (j == 0) { A.st_m[seg][b] = m_b; A.st_d[seg][b] = d_b; }
        if (A.last[seg]) {
            A.a_out[seg][gi] = A.sbn[seg][j] * __fdividef(accv, d_b) + A.abv[seg][j];
        }
    }
}

__global__ __launch_bounds__(256, 3) void rec_fused(RecFArgs A) {
    __shared__ float xs[TC * 64];
    __shared__ float hs[2][64];
    __shared__ float zs[4][64];
    int seg = blockIdx.x >> 10;
    int b   = blockIdx.x & 1023;
    if (A.K[seg] == 32) rec_seg<32>(A, seg, b, threadIdx.x, xs, hs, zs);
    else                rec_seg<64>(A, seg, b, threadIdx.x, xs, hs, zs);
}

// ---------------- final: out[b] = db + sum_{l,j} a[l][b][j]*dw[l*64+j] ----------------
__global__ void final_kernel(const float* __restrict__ a, const float* __restrict__ dw,
                             const float* __restrict__ db, float* __restrict__ out) {
    int b = blockIdx.x * blockDim.x + threadIdx.x;
    if (b >= BB) return;
    float acc = db[0];
    for (int l = 0; l < 3; ++l)
        for (int j = 0; j < HH; ++j)
            acc += a[(l * BB + b) * HH + j] * dw[l * HH + j];
    out[b] = acc;
}

extern "C" void kernel_launch(void* const* d_in, const int* in_sizes, int n_in,
                              void* d_out, int out_size, void* d_ws, size_t ws_size,
                              hipStream_t stream) {
    (void)in_sizes; (void)n_in; (void)out_size; (void)ws_size;
    const float* x = (const float*)d_in[0];
    const float* w[3]    = {(const float*)d_in[1],  (const float*)d_in[10], (const float*)d_in[19]};
    const float* uu[3]   = {(const float*)d_in[2],  (const float*)d_in[11], (const float*)d_in[20]};
    const float* bi[3]   = {(const float*)d_in[3],  (const float*)d_in[12], (const float*)d_in[21]};
    const float* gam[3]  = {(const float*)d_in[4],  (const float*)d_in[13], (const float*)d_in[22]};
    const float* bet[3]  = {(const float*)d_in[5],  (const float*)d_in[14], (const float*)d_in[23]};
    const float* mea[3]  = {(const float*)d_in[6],  (const float*)d_in[15], (const float*)d_in[24]};
    const float* var[3]  = {(const float*)d_in[7],  (const float*)d_in[16], (const float*)d_in[25]};
    const float* atw[3]  = {(const float*)d_in[8],  (const float*)d_in[17], (const float*)d_in[26]};
    const float* atv[3]  = {(const float*)d_in[9],  (const float*)d_in[18], (const float*)d_in[27]};
    const float* dw = (const float*)d_in[28];
    const float* db = (const float*)d_in[29];

    float* ws = (float*)d_ws;
    size_t off = 0;
    // cross-layer h buffers, parity double-buffered: Hb[layer][parity]
    float* Hb[2][2];
    for (int l = 0; l < 2; ++l)
        for (int p = 0; p < 2; ++p) { Hb[l][p] = ws + off; off += (size_t)BB * TC * HH; }
    float* st_h  = ws + off; off += 3 * BB * HH;
    float* st_c  = ws + off; off += 3 * BB * HH;
    float* st_ac = ws + off; off += 3 * BB * HH;
    float* st_m  = ws + off; off += 3 * BB;
    float* st_d  = ws + off; off += 3 * BB;
    float* s_ws  = ws + off; off += 3 * HH;
    float* ab_ws = ws + off; off += 3 * HH;
    float* wv_ws = ws + off; off += 3 * HH;
    float* W2p   = ws + off; off += HH * GG;
    float* W3p   = ws + off; off += HH * GG;
    float* b2p   = ws + off; off += GG;
    float* b3p   = ws + off; off += GG;
    float* a_ws  = ws + off; off += 3 * BB * HH;

    for (int l = 0; l < 3; ++l)
        fold1_kernel<<<1, 64, 0, stream>>>(gam[l], bet[l], mea[l], var[l], atw[l], atv[l],
                                           s_ws + l * HH, ab_ws + l * HH, wv_ws + l * HH);
    fold2_kernel<<<1, 256, 0, stream>>>(w[1], bi[1], s_ws + 0 * HH, ab_ws + 0 * HH, W2p, b2p);
    fold2_kernel<<<1, 256, 0, stream>>>(w[2], bi[2], s_ws + 1 * HH, ab_ws + 1 * HH, W3p, b3p);
    init_kernel<<<(3 * BB * HH + 255) / 256, 256, 0, stream>>>(st_h, st_c, st_ac, st_m, st_d);

    const float* Wl[3] = {w[0], W2p, W3p};
    const float* bl[3] = {bi[0], b2p, b3p};

    // software pipeline: at step s, layer l processes chunk s-l
    for (int s = 0; s <= NCHUNK - 1 + 2; ++s) {
        RecFArgs ra;
        int nseg = 0;
        for (int l = 0; l < 3; ++l) {
            int cpos = s - l;
            if (cpos < 0 || cpos >= NCHUNK) continue;
            if (l == 0) {
                ra.xin[nseg] = x + (size_t)cpos * TC * FF;
                ra.sB[nseg] = (long)TT * FF;
                ra.K[nseg] = 32;
            } else {
                ra.xin[nseg] = Hb[l - 1][(s & 1) ^ 1];   // written by layer l-1 at step s-1
                ra.sB[nseg] = (long)TC * HH;
                ra.K[nseg] = 64;
            }
            ra.W[nseg] = Wl[l]; ra.U[nseg] = uu[l]; ra.bias[nseg] = bl[l];
            ra.Hout[nseg] = (l < 2) ? Hb[l][s & 1] : (float*)0;
            ra.st_h[nseg] = st_h + l * BB * HH;
            ra.st_c[nseg] = st_c + l * BB * HH;
            ra.st_acc[nseg] = st_ac + l * BB * HH;
            ra.st_m[nseg] = st_m + l * BB;
            ra.st_d[nseg] = st_d + l * BB;
            ra.wv[nseg]  = wv_ws + l * HH;
            ra.abv[nseg] = ab_ws + l * HH;
            ra.sbn[nseg] = s_ws + l * HH;
            ra.a_out[nseg] = a_ws + l * BB * HH;
            ra.last[nseg] = (cpos == NCHUNK - 1) ? 1 : 0;
            ++nseg;
        }
        if (!nseg) continue;
        rec_fused<<<nseg * BB, 256, 0, stream>>>(ra);
    }
    final_kernel<<<(BB + 255) / 256, 256, 0, stream>>>(a_ws, dw, db, (float*)d_out);
}

// Round 5
// 1910.198 us; speedup vs baseline: 2.3733x; 1.3928x over previous
//
#include <hip/hip_runtime.h>
#include <math.h>

#define BB 1024
#define TT 512
#define FF 32
#define HH 64
#define GG 256   // 4H
#define TC 64
#define NCHUNK (TT/TC)   // 8
#define EPSBN 1e-3f

// ---------------- fold1: per-layer BN vectors + attention vector ----------------
__global__ void fold1_kernel(const float* __restrict__ gamma, const float* __restrict__ beta,
                             const float* __restrict__ mean, const float* __restrict__ var,
                             const float* __restrict__ attw, const float* __restrict__ attv,
                             float* __restrict__ s_out, float* __restrict__ ab_out,
                             float* __restrict__ wv_out) {
    int d = threadIdx.x; // 64 threads
    float s = gamma[d] * rsqrtf(var[d] + EPSBN);
    float ab = beta[d] - mean[d] * s;
    float wvr = 0.f;
    for (int e = 0; e < HH; ++e) wvr += attw[d * HH + e] * attv[e];
    s_out[d] = s;
    ab_out[d] = ab;
    wv_out[d] = s * wvr;
}

// ---------------- fold2: fold previous layer's BN into next W, b ----------------
__global__ void fold2_kernel(const float* __restrict__ W, const float* __restrict__ b,
                             const float* __restrict__ s_prev, const float* __restrict__ ab_prev,
                             float* __restrict__ Wp, float* __restrict__ bp) {
    int g = threadIdx.x; // 256 threads
    float bacc = b[g];
    for (int d = 0; d < HH; ++d) {
        float w = W[d * GG + g];
        bacc += ab_prev[d] * w;
        Wp[d * GG + g] = s_prev[d] * w;
    }
    bp[g] = bacc;
}

// ---------------- init per-call state ----------------
__global__ void init_kernel(float* st_h, float* st_c, float* st_acc, float* st_m, float* st_d) {
    int i = blockIdx.x * blockDim.x + threadIdx.x;
    int n = 3 * BB * HH;
    if (i < n) { st_h[i] = 0.f; st_c[i] = 0.f; st_acc[i] = 0.f; }
    if (i < 3 * BB) { st_m[i] = -3.0e38f; st_d[i] = 0.f; }
}

// ---------------- fused recurrent kernel ----------------
// Block = 4 waves = 1 batch row of 1 layer-chunk. Wave w = gate w; lane j = unit j.
// Weights (wx[K], u[64]) VGPR-resident (launch_bounds(256,2) -> cap 256 regs).
// One barrier per timestep: parity-dbuf gate exchange; redundant c/h update per wave;
// per-wave private h broadcast buffer. Attention hoisted to a per-chunk epilogue.
struct RecFArgs {
    const float* xin[3]; long sB[3]; int K[3];
    const float* W[3]; const float* U[3]; const float* bias[3];
    float* Hout[3];              // nullptr -> skip
    float* st_h[3]; float* st_c[3]; float* st_acc[3];
    float* st_m[3]; float* st_d[3];
    const float* wv[3]; const float* abv[3]; const float* sbn[3];
    float* a_out[3];
    int last[3];
};

template<int K>
__device__ __forceinline__ void rec_seg(const RecFArgs& A, int seg, int b, int tid,
                                        float* xs, float* Hl, float* zsf,
                                        float* hwf, float* wv_lds, float* score_lds) {
    const int w = tid >> 6, j = tid & 63;
    const int col = (w << 6) + j;

    const float* Wp = A.W[seg];
    const float* Up = A.U[seg];
    float wx[K], u[64];
#pragma unroll
    for (int k = 0; k < K; ++k) wx[k] = Wp[k * GG + col];
#pragma unroll
    for (int k = 0; k < 64; ++k) u[k] = Up[k * GG + col];
    const float bg = A.bias[seg][col];

    // stage x chunk (contiguous TC*K floats per batch row)
    const float4* xb4 = reinterpret_cast<const float4*>(A.xin[seg] + (long)b * A.sB[seg]);
    constexpr int NF4 = TC * K / 4;
    for (int i = tid; i < NF4; i += 256)
        reinterpret_cast<float4*>(xs)[i] = xb4[i];
    if (tid < 64) wv_lds[tid] = A.wv[seg][tid];

    const int gi = (b << 6) + j;
    float c = A.st_c[seg][gi];
    float h = A.st_h[seg][gi];
    float accv = 0.f, m_b = 0.f, d_b = 0.f;
    if (w == 0) { accv = A.st_acc[seg][gi]; m_b = A.st_m[seg][b]; d_b = A.st_d[seg][b]; }
    hwf[(w << 6) + j] = h;      // per-wave private h buffer
    __syncthreads();

    float* Hob = A.Hout[seg] ? A.Hout[seg] + (size_t)b * TC * HH + j : (float*)0;

#pragma unroll 2
    for (int t = 0; t < TC; ++t) {
        const float* xr = xs + t * K;
        float a0 = bg, a1 = 0.f;
#pragma unroll
        for (int k8 = 0; k8 < K / 8; ++k8) {
            float4 xA = *reinterpret_cast<const float4*>(xr + k8 * 8);
            float4 xB = *reinterpret_cast<const float4*>(xr + k8 * 8 + 4);
            a0 = fmaf(xA.x, wx[k8*8+0], a0); a1 = fmaf(xA.y, wx[k8*8+1], a1);
            a0 = fmaf(xA.z, wx[k8*8+2], a0); a1 = fmaf(xA.w, wx[k8*8+3], a1);
            a0 = fmaf(xB.x, wx[k8*8+4], a0); a1 = fmaf(xB.y, wx[k8*8+5], a1);
            a0 = fmaf(xB.z, wx[k8*8+6], a0); a1 = fmaf(xB.w, wx[k8*8+7], a1);
        }
        const float* hp = hwf + (w << 6);
#pragma unroll
        for (int k8 = 0; k8 < 8; ++k8) {
            float4 hA = *reinterpret_cast<const float4*>(hp + k8 * 8);
            float4 hB = *reinterpret_cast<const float4*>(hp + k8 * 8 + 4);
            a0 = fmaf(hA.x, u[k8*8+0], a0); a1 = fmaf(hA.y, u[k8*8+1], a1);
            a0 = fmaf(hA.z, u[k8*8+2], a0); a1 = fmaf(hA.w, u[k8*8+3], a1);
            a0 = fmaf(hB.x, u[k8*8+4], a0); a1 = fmaf(hB.y, u[k8*8+5], a1);
            a0 = fmaf(hB.z, u[k8*8+6], a0); a1 = fmaf(hB.w, u[k8*8+7], a1);
        }
        float acc = a0 + a1;
        float z = (w == 2) ? fmaxf(acc, 0.f)
                           : __fdividef(1.f, 1.f + __expf(-acc));
        float* zp = zsf + ((t & 1) << 8);
        zp[(w << 6) + j] = z;
        __syncthreads();                         // the ONLY barrier per timestep

        float zi = zp[j], zf = zp[64 + j], zg = zp[128 + j], zo = zp[192 + j];
        c = fmaf(zf, c, zi * zg);
        h = zo * fmaxf(c, 0.f);
        hwf[(w << 6) + j] = h;                   // own-wave buffer: no barrier needed
        if (w == 3) Hl[t * 65 + j] = h;          // for attention epilogue
        if (w == 1 && Hob) Hob[t * HH] = h;      // for next layer
    }
    __syncthreads();

    // ---- per-chunk attention epilogue (flash merge) ----
    // Phase A: scores[t] = sum_j H[t][j]*wv[j]
    {
        int tq = tid >> 2, q = tid & 3;
        float part = 0.f;
#pragma unroll
        for (int i = 0; i < 16; ++i)
            part = fmaf(Hl[tq * 65 + q * 16 + i], wv_lds[q * 16 + i], part);
        part += __shfl_xor(part, 1);
        part += __shfl_xor(part, 2);
        if (q == 0) score_lds[tq] = part;
    }
    __syncthreads();
    // Phase B: chunk max + exp + denom (all waves compute identically)
    float s = score_lds[j];
    float Mc = s;
#pragma unroll
    for (int off = 1; off < 64; off <<= 1) Mc = fmaxf(Mc, __shfl_xor(Mc, off));
    float p = __expf(s - Mc);
    float Dc = p;
#pragma unroll
    for (int off = 1; off < 64; off <<= 1) Dc += __shfl_xor(Dc, off);
    // Phase C: partial weighted sum over this wave's 16 timesteps
    {
        int wu = __builtin_amdgcn_readfirstlane(w);
        float pacc = 0.f;
#pragma unroll
        for (int tt = 0; tt < 16; ++tt) {
            float ptt = __int_as_float(
                __builtin_amdgcn_readlane(__float_as_int(p), wu * 16 + tt));
            pacc = fmaf(ptt, Hl[(wu * 16 + tt) * 65 + j], pacc);
        }
        zsf[(w << 6) + j] = pacc;                // reuse zs[0] for partials
    }
    __syncthreads();
    // Phase D: merge with running state (wave 0); store states
    if (w == 2) { A.st_c[seg][gi] = c; A.st_h[seg][gi] = h; }
    if (w == 0) {
        float Ac = zsf[j] + zsf[64 + j] + zsf[128 + j] + zsf[192 + j];
        float mnew = fmaxf(m_b, Mc);
        float corr = __expf(m_b - mnew);
        float pc = __expf(Mc - mnew);
        d_b = d_b * corr + Dc * pc;
        accv = fmaf(accv, corr, Ac * pc);
        m_b = mnew;
        A.st_acc[seg][gi] = accv;
        if (j == 0) { A.st_m[seg][b] = m_b; A.st_d[seg][b] = d_b; }
        if (A.last[seg])
            A.a_out[seg][gi] = A.sbn[seg][j] * __fdividef(accv, d_b) + A.abv[seg][j];
    }
}

__global__ __launch_bounds__(256, 2) void rec_fused(RecFArgs A) {
    __shared__ float xs[TC * 64];        // 16 KB
    __shared__ float Hl[TC * 65];        // 16.6 KB (padded, bank-conflict-free)
    __shared__ float zsf[2 * 4 * 64];    // 2 KB (parity double-buffered gates)
    __shared__ float hwf[4 * 64];        // 1 KB (per-wave h broadcast)
    __shared__ float wv_lds[64];
    __shared__ float score_lds[64];
    int seg = blockIdx.x >> 10;
    int b   = blockIdx.x & 1023;
    if (A.K[seg] == 32) rec_seg<32>(A, seg, b, threadIdx.x, xs, Hl, zsf, hwf, wv_lds, score_lds);
    else                rec_seg<64>(A, seg, b, threadIdx.x, xs, Hl, zsf, hwf, wv_lds, score_lds);
}

// ---------------- final: out[b] = db + sum_{l,j} a[l][b][j]*dw[l*64+j] ----------------
__global__ void final_kernel(const float* __restrict__ a, const float* __restrict__ dw,
                             const float* __restrict__ db, float* __restrict__ out) {
    int b = blockIdx.x * blockDim.x + threadIdx.x;
    if (b >= BB) return;
    float acc = db[0];
    for (int l = 0; l < 3; ++l)
        for (int j = 0; j < HH; ++j)
            acc += a[(l * BB + b) * HH + j] * dw[l * HH + j];
    out[b] = acc;
}

extern "C" void kernel_launch(void* const* d_in, const int* in_sizes, int n_in,
                              void* d_out, int out_size, void* d_ws, size_t ws_size,
                              hipStream_t stream) {
    (void)in_sizes; (void)n_in; (void)out_size; (void)ws_size;
    const float* x = (const float*)d_in[0];
    const float* w[3]    = {(const float*)d_in[1],  (const float*)d_in[10], (const float*)d_in[19]};
    const float* uu[3]   = {(const float*)d_in[2],  (const float*)d_in[11], (const float*)d_in[20]};
    const float* bi[3]   = {(const float*)d_in[3],  (const float*)d_in[12], (const float*)d_in[21]};
    const float* gam[3]  = {(const float*)d_in[4],  (const float*)d_in[13], (const float*)d_in[22]};
    const float* bet[3]  = {(const float*)d_in[5],  (const float*)d_in[14], (const float*)d_in[23]};
    const float* mea[3]  = {(const float*)d_in[6],  (const float*)d_in[15], (const float*)d_in[24]};
    const float* var[3]  = {(const float*)d_in[7],  (const float*)d_in[16], (const float*)d_in[25]};
    const float* atw[3]  = {(const float*)d_in[8],  (const float*)d_in[17], (const float*)d_in[26]};
    const float* atv[3]  = {(const float*)d_in[9],  (const float*)d_in[18], (const float*)d_in[27]};
    const float* dw = (const float*)d_in[28];
    const float* db = (const float*)d_in[29];

    float* ws = (float*)d_ws;
    size_t off = 0;
    // cross-layer h buffers, parity double-buffered: Hb[layer][parity]
    float* Hb[2][2];
    for (int l = 0; l < 2; ++l)
        for (int p = 0; p < 2; ++p) { Hb[l][p] = ws + off; off += (size_t)BB * TC * HH; }
    float* st_h  = ws + off; off += 3 * BB * HH;
    float* st_c  = ws + off; off += 3 * BB * HH;
    float* st_ac = ws + off; off += 3 * BB * HH;
    float* st_m  = ws + off; off += 3 * BB;
    float* st_d  = ws + off; off += 3 * BB;
    float* s_ws  = ws + off; off += 3 * HH;
    float* ab_ws = ws + off; off += 3 * HH;
    float* wv_ws = ws + off; off += 3 * HH;
    float* W2p   = ws + off; off += HH * GG;
    float* W3p   = ws + off; off += HH * GG;
    float* b2p   = ws + off; off += GG;
    float* b3p   = ws + off; off += GG;
    float* a_ws  = ws + off; off += 3 * BB * HH;

    for (int l = 0; l < 3; ++l)
        fold1_kernel<<<1, 64, 0, stream>>>(gam[l], bet[l], mea[l], var[l], atw[l], atv[l],
                                           s_ws + l * HH, ab_ws + l * HH, wv_ws + l * HH);
    fold2_kernel<<<1, 256, 0, stream>>>(w[1], bi[1], s_ws + 0 * HH, ab_ws + 0 * HH, W2p, b2p);
    fold2_kernel<<<1, 256, 0, stream>>>(w[2], bi[2], s_ws + 1 * HH, ab_ws + 1 * HH, W3p, b3p);
    init_kernel<<<(3 * BB * HH + 255) / 256, 256, 0, stream>>>(st_h, st_c, st_ac, st_m, st_d);

    const float* Wl[3] = {w[0], W2p, W3p};
    const float* bl[3] = {bi[0], b2p, b3p};

    // software pipeline: at step s, layer l processes chunk s-l
    for (int s = 0; s <= NCHUNK - 1 + 2; ++s) {
        RecFArgs ra;
        int nseg = 0;
        for (int l = 0; l < 3; ++l) {
            int cpos = s - l;
            if (cpos < 0 || cpos >= NCHUNK) continue;
            if (l == 0) {
                ra.xin[nseg] = x + (size_t)cpos * TC * FF;
                ra.sB[nseg] = (long)TT * FF;
                ra.K[nseg] = 32;
            } else {
                ra.xin[nseg] = Hb[l - 1][(s & 1) ^ 1];   // written by layer l-1 at step s-1
                ra.sB[nseg] = (long)TC * HH;
                ra.K[nseg] = 64;
            }
            ra.W[nseg] = Wl[l]; ra.U[nseg] = uu[l]; ra.bias[nseg] = bl[l];
            ra.Hout[nseg] = (l < 2) ? Hb[l][s & 1] : (float*)0;
            ra.st_h[nseg] = st_h + l * BB * HH;
            ra.st_c[nseg] = st_c + l * BB * HH;
            ra.st_acc[nseg] = st_ac + l * BB * HH;
            ra.st_m[nseg] = st_m + l * BB;
            ra.st_d[nseg] = st_d + l * BB;
            ra.wv[nseg]  = wv_ws + l * HH;
            ra.abv[nseg] = ab_ws + l * HH;
            ra.sbn[nseg] = s_ws + l * HH;
            ra.a_out[nseg] = a_ws + l * BB * HH;
            ra.last[nseg] = (cpos == NCHUNK - 1) ? 1 : 0;
            ++nseg;
        }
        if (!nseg) continue;
        rec_fused<<<nseg * BB, 256, 0, stream>>>(ra);
    }
    final_kernel<<<(BB + 255) / 256, 256, 0, stream>>>(a_ws, dw, db, (float*)d_out);
}